// Round 4
// baseline (143.249 us; speedup 1.0000x reference)
//
#include <hip/hip_runtime.h>
#include <hip/hip_bf16.h>

// SubnetGate = gathered grouped GEMM (B=16384, K=512, N=512, E=8, col 0).
// R4: B-fragments direct from global (Wt is 4MB, L2-resident -> loads stay in
// flight across barriers); A-only LDS, double-buffered (one barrier per kt);
// compact tile queue (no empty blocks).
//
// ws layout:
//   [0,    32)          int counts[8]
//   [64,   68)          int ndesc
//   [128,  768)         int desc[160]            (e<<16 | mt)
//   [4096, 528384)      int rowlist[8][16384]
//   [528384, 4722688)   ushort Wt[8][512][512]   (W transposed: [e][n][k], bf16)

#define NROWS   16384
#define KDIM    512
#define NDIM    512
#define NEXP    8
#define BM      128
#define BN      128
#define BK      64
#define APAD    72                       // shorts per A row (144B stride)
#define WS_NDESC_OFF   64
#define WS_DESC_OFF    128
#define WS_ROWLIST_OFF 4096
#define WS_WT_OFF      (4096 + NEXP * NROWS * 4)

typedef __bf16        bf16x8 __attribute__((ext_vector_type(8)));
typedef float         f32x4  __attribute__((ext_vector_type(4)));
typedef unsigned int  u32x4  __attribute__((ext_vector_type(4)));

__device__ __forceinline__ unsigned int f2bf_u(float f) {
    unsigned int u = __builtin_bit_cast(unsigned int, f);
    return (u + 0x7FFFu + ((u >> 16) & 1u)) >> 16;   // RNE f32->bf16
}

__device__ __forceinline__ u32x4 pack8(f32x4 a, f32x4 b) {
    u32x4 p;
    p.x = f2bf_u(a.x) | (f2bf_u(a.y) << 16);
    p.y = f2bf_u(a.z) | (f2bf_u(a.w) << 16);
    p.z = f2bf_u(b.x) | (f2bf_u(b.y) << 16);
    p.w = f2bf_u(b.z) | (f2bf_u(b.w) << 16);
    return p;
}

__global__ void zero_kernel(int* __restrict__ gcnt) {
    if (threadIdx.x < NEXP) gcnt[threadIdx.x] = 0;
}

// blocks [0,512): transpose+cast one 64x64 tile of W into Wt[e][n][k] bf16.
// blocks [512,576): histogram+scatter 256 rows each into per-expert rowlists.
__global__ void prep_kernel(const float* __restrict__ W,
                            const int* __restrict__ groups,
                            int* __restrict__ gcnt,
                            int* __restrict__ rowlist,
                            unsigned short* __restrict__ Wt) {
    __shared__ unsigned short tl[64 * 66];
    __shared__ int lcnt[NEXP];
    __shared__ int lbase[NEXP];
    const int bid = blockIdx.x;
    const int tid = threadIdx.x;

    if (bid < 512) {
        const int e  = bid >> 6;
        const int ot = (bid >> 3) & 7;   // n-tile
        const int it = bid & 7;          // k-tile
        const float*    Wb  = W  + (size_t)e * (KDIM * NDIM);
        unsigned short* Wtb = Wt + (size_t)e * (KDIM * NDIM);
        #pragma unroll
        for (int itr = 0; itr < 16; ++itr) {
            int f = itr * 256 + tid;
            int r = f >> 6, c = f & 63;              // k-local, n-local
            tl[r * 66 + c] =
                (unsigned short)f2bf_u(Wb[(size_t)(it * 64 + r) * NDIM + ot * 64 + c]);
        }
        __syncthreads();
        #pragma unroll
        for (int itr = 0; itr < 16; ++itr) {
            int f = itr * 256 + tid;
            int r2 = f >> 6, c2 = f & 63;            // n-local, k-local
            Wtb[(size_t)(ot * 64 + r2) * KDIM + it * 64 + c2] = tl[c2 * 66 + r2];
        }
    } else {
        const int base = (bid - 512) * 256;
        if (tid < NEXP) lcnt[tid] = 0;
        __syncthreads();
        int r = base + tid;
        int e = groups[r * 2];                        // group_col = 0
        int pos = atomicAdd(&lcnt[e], 1);
        __syncthreads();
        if (tid < NEXP) lbase[tid] = atomicAdd(&gcnt[tid], lcnt[tid]);
        __syncthreads();
        rowlist[e * NROWS + lbase[e] + pos] = r;
    }
}

// Compact tile queue: desc[d] = (e<<16 | mt); total tiles = ndesc*4 (4 nt).
__global__ void plan_kernel(const int* __restrict__ counts,
                            int* __restrict__ ndesc,
                            int* __restrict__ desc) {
    if (threadIdx.x == 0) {
        int M = 0;
        for (int e = 0; e < NEXP; ++e) {
            int nmt = (counts[e] + BM - 1) / BM;
            for (int mt = 0; mt < nmt; ++mt) desc[M++] = (e << 16) | mt;
        }
        ndesc[0] = M;
    }
}

// Block = one tile (e, mt, nt) from the queue. 128x128 tile, K=512 in 8 steps.
// A: gathered f32 rows -> bf16 -> LDS, DOUBLE-buffered, gather for kt+1 issued
//    before computing kt (latency hidden under MFMA). One barrier per kt.
// B: 16B fragments straight from global Wt (L2-resident, no barrier deps).
// Wave w owns 64x64 quadrant; acc 4x4 f32x4.
__global__ __launch_bounds__(256, 3)
void gemm_kernel(const float* __restrict__ x,
                 const int* __restrict__ counts,
                 const int* __restrict__ rowlist,
                 const unsigned short* __restrict__ Wt,
                 const float* __restrict__ bias,
                 float* __restrict__ out,
                 const int* __restrict__ ndesc,
                 const int* __restrict__ desc) {
    __shared__ __align__(16) unsigned short Asm[2][BM * APAD];   // 2 x 18KB

    const int tid = threadIdx.x;
    const int w   = tid >> 6;
    const int ln  = tid & 63;
    const int q   = ln >> 4;
    const int l15 = ln & 15;
    const int wm  = (w >> 1) * 64;
    const int wn  = (w & 1) * 64;

    const int T = ndesc[0] * 4;
    for (int t = blockIdx.x; t < T; t += gridDim.x) {
        const int d  = t >> 2;
        const int nt = t & 3;
        const int de = desc[d];
        const int e  = de >> 16;
        const int mt = de & 0xffff;
        const int cnt = counts[e];
        const int rb  = mt * BM;
        int m_valid = cnt - rb;
        if (m_valid > BM) m_valid = BM;
        const int* rl = rowlist + e * NROWS + rb;

        // staging granule per thread: f=(i*256+tid): m=f>>3 (row), g=f&7 (8-float chunk)
        const float* srcp[4];
        int lm[4], lg[4];
        #pragma unroll
        for (int i = 0; i < 4; ++i) {
            int f = i * 256 + tid;
            lm[i] = f >> 3;
            lg[i] = f & 7;
            srcp[i] = (lm[i] < m_valid) ? (x + (size_t)rl[lm[i]] * KDIM + lg[i] * 8)
                                        : nullptr;
        }

        const unsigned short* We = Wt + (size_t)e * (KDIM * NDIM);
        // per-lane B row pointers (n = nt*128 + wn + ni*16 + l15)
        const unsigned short* brow[4];
        #pragma unroll
        for (int ni = 0; ni < 4; ++ni)
            brow[ni] = We + (size_t)(nt * BN + wn + ni * 16 + l15) * KDIM;

        f32x4 acc[4][4];
        #pragma unroll
        for (int mi = 0; mi < 4; ++mi)
            #pragma unroll
            for (int ni = 0; ni < 4; ++ni)
                acc[mi][ni] = (f32x4){0.f, 0.f, 0.f, 0.f};

        // ---- initial stage: kt=0 into buf 0
        #pragma unroll
        for (int i = 0; i < 4; ++i) {
            u32x4 p = {0u, 0u, 0u, 0u};
            if (srcp[i]) {
                f32x4 a = *(const f32x4*)(srcp[i]);
                f32x4 b = *(const f32x4*)(srcp[i] + 4);
                p = pack8(a, b);
            }
            *(u32x4*)&Asm[0][lm[i] * APAD + lg[i] * 8] = p;
        }
        __syncthreads();

        #pragma unroll 1
        for (int kt = 0; kt < 8; ++kt) {
            const int cur = kt & 1;
            // ---- prefetch gather for kt+1 (issued before compute; latency
            //      hidden under the MFMA block below)
            f32x4 ga[4], gb[4];
            if (kt < 7) {
                #pragma unroll
                for (int i = 0; i < 4; ++i) {
                    if (srcp[i]) {
                        const float* s = srcp[i] + (kt + 1) * BK;
                        ga[i] = *(const f32x4*)s;
                        gb[i] = *(const f32x4*)(s + 4);
                    }
                }
            }
            // ---- compute kt from Asm[cur]; B frags direct from global (L2)
            #pragma unroll
            for (int ks = 0; ks < 2; ++ks) {
                const int g = ks * 4 + q;            // k-chunk 0..7
                bf16x8 af[4], bfr[4];
                #pragma unroll
                for (int mi = 0; mi < 4; ++mi)
                    af[mi] = *(const bf16x8*)&Asm[cur][(wm + mi * 16 + l15) * APAD + g * 8];
                #pragma unroll
                for (int ni = 0; ni < 4; ++ni)
                    bfr[ni] = *(const bf16x8*)(brow[ni] + kt * BK + g * 8);
                #pragma unroll
                for (int mi = 0; mi < 4; ++mi)
                    #pragma unroll
                    for (int ni = 0; ni < 4; ++ni)
                        acc[mi][ni] = __builtin_amdgcn_mfma_f32_16x16x32_bf16(
                            af[mi], bfr[ni], acc[mi][ni], 0, 0, 0);
            }
            // ---- write prefetched kt+1 into the other buffer
            if (kt < 7) {
                #pragma unroll
                for (int i = 0; i < 4; ++i) {
                    u32x4 p = {0u, 0u, 0u, 0u};
                    if (srcp[i]) p = pack8(ga[i], gb[i]);
                    *(u32x4*)&Asm[cur ^ 1][lm[i] * APAD + lg[i] * 8] = p;
                }
            }
            __syncthreads();
        }

        // ---- epilogue: +bias, masked scatter (C/D: col=l15, row=q*4+r)
        int growv[16];
        #pragma unroll
        for (int mi = 0; mi < 4; ++mi)
            #pragma unroll
            for (int r = 0; r < 4; ++r) {
                int rloc = wm + mi * 16 + q * 4 + r;
                growv[mi * 4 + r] = (rloc < m_valid) ? rl[rloc] : -1;
            }
        const int ncol0 = nt * BN + wn;
        #pragma unroll
        for (int ni = 0; ni < 4; ++ni) {
            int col = ncol0 + ni * 16 + l15;
            float bv = bias[e * NDIM + col];
            #pragma unroll
            for (int mi = 0; mi < 4; ++mi)
                #pragma unroll
                for (int r = 0; r < 4; ++r) {
                    int gr = growv[mi * 4 + r];
                    if (gr >= 0) out[(size_t)gr * NDIM + col] = acc[mi][ni][r] + bv;
                }
        }
    }
}

extern "C" void kernel_launch(void* const* d_in, const int* in_sizes, int n_in,
                              void* d_out, int out_size, void* d_ws, size_t ws_size,
                              hipStream_t stream) {
    const float* x      = (const float*)d_in[0];   // (16384, 512) f32
    const int*   groups = (const int*)d_in[1];     // (16384, 2) i32
    const float* W      = (const float*)d_in[2];   // (8, 512, 512) f32
    const float* b      = (const float*)d_in[3];   // (8, 512) f32
    float*       out    = (float*)d_out;           // (16384, 512) f32

    char* ws = (char*)d_ws;
    int*            counts  = (int*)ws;
    int*            ndesc   = (int*)(ws + WS_NDESC_OFF);
    int*            desc    = (int*)(ws + WS_DESC_OFF);
    int*            rowlist = (int*)(ws + WS_ROWLIST_OFF);
    unsigned short* Wt      = (unsigned short*)(ws + WS_WT_OFF);

    zero_kernel<<<1, 64, 0, stream>>>(counts);
    prep_kernel<<<576, 256, 0, stream>>>(W, groups, counts, rowlist, Wt);
    plan_kernel<<<1, 64, 0, stream>>>(counts, ndesc, desc);
    gemm_kernel<<<544, 256, 0, stream>>>(x, counts, rowlist, Wt, b, out, ndesc, desc);
}

// Round 5
// 131.052 us; speedup vs baseline: 1.0931x; 1.0931x over previous
//
#include <hip/hip_runtime.h>
#include <hip/hip_bf16.h>

// SubnetGate = gathered grouped GEMM (B=16384, K=512, N=512, E=8, col 0).
// R5: pre-gather x into bf16 swizzle-tiled xg (separate streaming kernel),
// then a pure m97-style GEMM: both operands staged with linear async
// global_load_lds, BM=64 x BN=128 x BK=64, ~1030 working tiles, 24KB LDS.
//
// ws layout:
//   [0,32)      int counts[8]
//   [64,68)     int ndesc
//   [128,1184)  int desc[264]            (e<<16 | mt), BM=64 tiles
//   [4096,528384)      int rowlist[8][16384]
//   [528384,4722688)   ushort Wtile[8][4 nt][8 kt][128n x 64k bf16, swizzled]
//   [4722688,22024192) ushort xg[264 d][8 kt][64m x 64k bf16, swizzled]  (if ws allows)

#define NROWS   16384
#define KDIM    512
#define NDIM    512
#define NEXP    8
#define TILE_ELEMS 8192                  // B tile: 128n x 64k shorts (16KB)
#define ATILE_ELEMS 4096                 // A tile: 64m x 64k shorts (8KB)
#define MAX_DESC 264
#define WS_NDESC_OFF   64
#define WS_DESC_OFF    128
#define WS_ROWLIST_OFF 4096
#define WS_WT_OFF      (4096 + NEXP * NROWS * 4)
#define WS_XG_OFF      (WS_WT_OFF + NEXP * KDIM * NDIM * 2)
#define WS_NEED        ((size_t)WS_XG_OFF + (size_t)MAX_DESC * 8 * ATILE_ELEMS * 2)

typedef __bf16        bf16x8 __attribute__((ext_vector_type(8)));
typedef float         f32x4  __attribute__((ext_vector_type(4)));
typedef unsigned int  u32x4  __attribute__((ext_vector_type(4)));

__device__ __forceinline__ unsigned int f2bf_u(float f) {
    unsigned int u = __builtin_bit_cast(unsigned int, f);
    return (u + 0x7FFFu + ((u >> 16) & 1u)) >> 16;   // RNE f32->bf16
}
__device__ __forceinline__ unsigned int pack2(float a, float b) {
    return f2bf_u(a) | (f2bf_u(b) << 16);
}
__device__ __forceinline__ u32x4 pack8(f32x4 a, f32x4 b) {
    u32x4 p;
    p.x = pack2(a.x, a.y); p.y = pack2(a.z, a.w);
    p.z = pack2(b.x, b.y); p.w = pack2(b.z, b.w);
    return p;
}
__device__ __forceinline__ void gl_lds16(const void* g, void* l) {
    __builtin_amdgcn_global_load_lds(
        (const __attribute__((address_space(1))) unsigned int*)g,
        (__attribute__((address_space(3))) unsigned int*)l, 16, 0, 0);
}

__global__ void zero_kernel(int* __restrict__ gcnt) {
    if (threadIdx.x < NEXP) gcnt[threadIdx.x] = 0;
}

// blocks [0,256): build one 16KB swizzled B-tile (e,nt,kt); granule (n,g) at
//   shorts n*64 + (g^(n&7))*8. [verified R3: passed absmax 0.031]
// blocks [256,320): histogram+scatter rows into per-expert rowlists.
__global__ void prep_kernel(const float* __restrict__ W,
                            const int* __restrict__ groups,
                            int* __restrict__ gcnt,
                            int* __restrict__ rowlist,
                            unsigned short* __restrict__ Wtile) {
    __shared__ __align__(16) unsigned short tl[TILE_ELEMS];
    __shared__ int lcnt[NEXP];
    __shared__ int lbase[NEXP];
    const int bid = blockIdx.x;
    const int tid = threadIdx.x;

    if (bid < 256) {
        const int e  = bid >> 5;         // bid = e*32 + nt*8 + kt
        const int nt = (bid >> 3) & 3;
        const int kt = bid & 7;
        const float* Wb = W + (size_t)e * (KDIM * NDIM);
        #pragma unroll
        for (int i = 0; i < 4; ++i) {
            int f = i * 256 + tid;       // granule id 0..1023
            int n = f & 127;
            int g = f >> 7;
            int col = nt * 128 + n;
            unsigned int p[4];
            #pragma unroll
            for (int jj = 0; jj < 4; ++jj) {
                int k0 = kt * 64 + g * 8 + jj * 2;
                p[jj] = pack2(Wb[(size_t)k0 * NDIM + col],
                              Wb[(size_t)(k0 + 1) * NDIM + col]);
            }
            *(u32x4*)&tl[n * 64 + (g ^ (n & 7)) * 8] = *(const u32x4*)p;
        }
        __syncthreads();
        unsigned short* dst = Wtile + (size_t)bid * TILE_ELEMS;
        #pragma unroll
        for (int i = 0; i < 4; ++i) {
            int off = (i * 256 + tid) * 8;
            *(u32x4*)&dst[off] = *(const u32x4*)&tl[off];
        }
    } else {
        const int base = (bid - 256) * 256;
        if (tid < NEXP) lcnt[tid] = 0;
        __syncthreads();
        int r = base + tid;
        int e = groups[r * 2];           // group_col = 0
        int pos = atomicAdd(&lcnt[e], 1);
        __syncthreads();
        if (tid < NEXP) lbase[tid] = atomicAdd(&gcnt[tid], lcnt[tid]);
        __syncthreads();
        rowlist[e * NROWS + lbase[e] + pos] = r;
    }
}

// desc[d] = (e<<16 | mt) for BM=64 m-tiles; ndesc = total descs.
__global__ void plan_kernel(const int* __restrict__ counts,
                            int* __restrict__ ndesc,
                            int* __restrict__ desc) {
    if (threadIdx.x == 0) {
        int M = 0;
        for (int e = 0; e < NEXP; ++e) {
            int nmt = (counts[e] + 63) >> 6;
            for (int mt = 0; mt < nmt && M < MAX_DESC; ++mt)
                desc[M++] = (e << 16) | mt;
        }
        ndesc[0] = M;
    }
}

// Block (d,kt): gather 64 rows x 64 k of x, cast bf16, write one 8KB swizzled
// A-tile: granule (m,g) at shorts m*64 + (g^(m&7))*8. Tail rows zero-filled.
__global__ __launch_bounds__(256, 4)
void gather_kernel(const float* __restrict__ x,
                   const int* __restrict__ counts,
                   const int* __restrict__ rowlist,
                   const int* __restrict__ ndesc,
                   const int* __restrict__ desc,
                   unsigned short* __restrict__ xg) {
    const int bid = blockIdx.x;
    const int d  = bid >> 3;
    const int kt = bid & 7;
    if (d >= ndesc[0]) return;
    const int de = desc[d];
    const int e  = de >> 16;
    const int mt = de & 0xffff;
    const int cnt = counts[e];
    int m_valid = cnt - mt * 64;
    if (m_valid > 64) m_valid = 64;
    const int* rl = rowlist + e * NROWS + mt * 64;

    const int t = threadIdx.x;
    const int m = t >> 2;
    const int c = t & 3;                 // quarter: floats [c*16, c*16+16)

    u32x4 lo = {0u,0u,0u,0u}, hi = {0u,0u,0u,0u};
    if (m < m_valid) {
        const float* s = x + (size_t)rl[m] * KDIM + kt * 64 + c * 16;
        f32x4 v0 = *(const f32x4*)(s);
        f32x4 v1 = *(const f32x4*)(s + 4);
        f32x4 v2 = *(const f32x4*)(s + 8);
        f32x4 v3 = *(const f32x4*)(s + 12);
        lo = pack8(v0, v1);              // granule g0 = 2c
        hi = pack8(v2, v3);              // granule g1 = 2c+1
    }
    const int p = m & 7;
    unsigned short* tile = xg + ((size_t)d * 8 + kt) * ATILE_ELEMS;
    // pair {2c^p, (2c+1)^p} occupies aligned 32B slot at base 2c^(p&6);
    // halves swapped when p is odd.
    int base = (m * 8 + ((2 * c) ^ (p & 6))) * 8;    // shorts
    if (p & 1) {
        *(u32x4*)&tile[base]     = hi;
        *(u32x4*)&tile[base + 8] = lo;
    } else {
        *(u32x4*)&tile[base]     = lo;
        *(u32x4*)&tile[base + 8] = hi;
    }
}

// m97-style GEMM: tile (d, nt) = 64 gathered rows x 128 cols, K=512 in 8 steps.
// A and B staged with linear async global_load_lds from pre-swizzled tiles.
// Wave w: wm=(w>>1)*32, wn=(w&1)*64; acc 2x4 f32x4.
__global__ __launch_bounds__(256, 4)
void gemm_tiled(const unsigned short* __restrict__ xg,
                const int* __restrict__ counts,
                const int* __restrict__ rowlist,
                const unsigned short* __restrict__ Wtile,
                const float* __restrict__ bias,
                float* __restrict__ out,
                const int* __restrict__ ndesc,
                const int* __restrict__ desc) {
    __shared__ __align__(16) unsigned short Asm[ATILE_ELEMS];   // 8KB
    __shared__ __align__(16) unsigned short Bsm[TILE_ELEMS];    // 16KB

    const int tid = threadIdx.x;
    const int w   = tid >> 6;
    const int ln  = tid & 63;
    const int q   = ln >> 4;
    const int l15 = ln & 15;
    const int wm  = (w >> 1) * 32;
    const int wn  = (w & 1) * 64;

    const int T = ndesc[0] * 4;
    for (int tix = blockIdx.x; tix < T; tix += gridDim.x) {
        const int d  = tix >> 2;
        const int nt = tix & 3;
        const int de = desc[d];
        const int e  = de >> 16;
        const int mt = de & 0xffff;
        const int cnt = counts[e];
        int m_valid = cnt - mt * 64;
        if (m_valid > 64) m_valid = 64;
        const int* rl = rowlist + e * NROWS + mt * 64;

        const unsigned short* atile = xg + (size_t)d * 8 * ATILE_ELEMS;
        const unsigned short* btile = Wtile + (size_t)(e * 32 + nt * 8) * TILE_ELEMS;

        f32x4 acc[2][4];
        #pragma unroll
        for (int mi = 0; mi < 2; ++mi)
            #pragma unroll
            for (int ni = 0; ni < 4; ++ni)
                acc[mi][ni] = (f32x4){0.f, 0.f, 0.f, 0.f};

        #pragma unroll 1
        for (int kt = 0; kt < 8; ++kt) {
            const unsigned short* asrc = atile + kt * ATILE_ELEMS;
            const unsigned short* bsrc = btile + kt * TILE_ELEMS;
            #pragma unroll
            for (int i = 0; i < 2; ++i) {
                int off = (i * 256 + tid) * 8;
                gl_lds16(asrc + off, &Asm[off]);
            }
            #pragma unroll
            for (int i = 0; i < 4; ++i) {
                int off = (i * 256 + tid) * 8;
                gl_lds16(bsrc + off, &Bsm[off]);
            }
            __syncthreads();
            #pragma unroll
            for (int ks = 0; ks < 2; ++ks) {
                const int g = ks * 4 + q;
                bf16x8 af[2], bfr[4];
                #pragma unroll
                for (int mi = 0; mi < 2; ++mi) {
                    int r = wm + mi * 16 + l15;
                    af[mi] = *(const bf16x8*)&Asm[(r * 8 + (g ^ (r & 7))) * 8];
                }
                #pragma unroll
                for (int ni = 0; ni < 4; ++ni) {
                    int n = wn + ni * 16 + l15;
                    bfr[ni] = *(const bf16x8*)&Bsm[n * 64 + (g ^ (n & 7)) * 8];
                }
                #pragma unroll
                for (int mi = 0; mi < 2; ++mi)
                    #pragma unroll
                    for (int ni = 0; ni < 4; ++ni)
                        acc[mi][ni] = __builtin_amdgcn_mfma_f32_16x16x32_bf16(
                            af[mi], bfr[ni], acc[mi][ni], 0, 0, 0);
            }
            __syncthreads();
        }

        // epilogue: +bias, masked scatter (C/D: col=l15, row=q*4+r)
        int growv[8];
        #pragma unroll
        for (int mi = 0; mi < 2; ++mi)
            #pragma unroll
            for (int r = 0; r < 4; ++r) {
                int rloc = wm + mi * 16 + q * 4 + r;
                growv[mi * 4 + r] = (rloc < m_valid) ? rl[rloc] : -1;
            }
        const int ncol0 = nt * 128 + wn;
        #pragma unroll
        for (int ni = 0; ni < 4; ++ni) {
            int col = ncol0 + ni * 16 + l15;
            float bv = bias[e * NDIM + col];
            #pragma unroll
            for (int mi = 0; mi < 2; ++mi)
                #pragma unroll
                for (int r = 0; r < 4; ++r) {
                    int gr = growv[mi * 4 + r];
                    if (gr >= 0) out[(size_t)gr * NDIM + col] = acc[mi][ni][r] + bv;
                }
        }
    }
}

// Fallback (ws too small for xg): R3-verified 48us gemm. BM=BN=128, in-kernel
// A gather+pack, B via global_load_lds from Wtile.
__global__ __launch_bounds__(256, 2)
void gemm_fb(const float* __restrict__ x,
             const int* __restrict__ counts,
             const int* __restrict__ rowlist,
             const unsigned short* __restrict__ Wtile,
             const float* __restrict__ bias,
             float* __restrict__ out) {
    __shared__ __align__(16) unsigned short Asm[128 * 72];
    __shared__ __align__(16) unsigned short Bsm[TILE_ELEMS];

    const int bid = blockIdx.x;
    const int e   = bid >> 9;
    const int mt  = (bid >> 2) & 127;
    const int nt  = bid & 3;
    const int cnt = counts[e];
    const int rb  = mt * 128;
    if (rb >= cnt) return;
    int m_valid = cnt - rb;
    if (m_valid > 128) m_valid = 128;
    const int* rl = rowlist + e * NROWS + rb;

    const int tid = threadIdx.x;
    const int w   = tid >> 6;
    const int ln  = tid & 63;
    const int q   = ln >> 4;
    const int l15 = ln & 15;
    const int wm  = (w >> 1) * 64;
    const int wn  = (w & 1) * 64;

    const float* srcp[4];
    int lm[4], lg[4];
    #pragma unroll
    for (int i = 0; i < 4; ++i) {
        int f = i * 256 + tid;
        lm[i] = f >> 3;
        lg[i] = f & 7;
        srcp[i] = (lm[i] < m_valid) ? (x + (size_t)rl[lm[i]] * KDIM + lg[i] * 8)
                                    : nullptr;
    }
    const unsigned short* wt = Wtile + (size_t)(e * 32 + nt * 8) * TILE_ELEMS;

    f32x4 acc[4][4];
    #pragma unroll
    for (int mi = 0; mi < 4; ++mi)
        #pragma unroll
        for (int ni = 0; ni < 4; ++ni)
            acc[mi][ni] = (f32x4){0.f, 0.f, 0.f, 0.f};

    for (int kt = 0; kt < 8; ++kt) {
        const unsigned short* wsrc = wt + (size_t)kt * TILE_ELEMS;
        #pragma unroll
        for (int i = 0; i < 4; ++i) {
            int off = (i * 256 + tid) * 8;
            gl_lds16(wsrc + off, &Bsm[off]);
        }
        #pragma unroll
        for (int i = 0; i < 4; ++i) {
            u32x4 p = {0u, 0u, 0u, 0u};
            if (srcp[i]) {
                const float* s = srcp[i] + kt * 64;
                p = pack8(*(const f32x4*)s, *(const f32x4*)(s + 4));
            }
            *(u32x4*)&Asm[lm[i] * 72 + lg[i] * 8] = p;
        }
        __syncthreads();
        #pragma unroll
        for (int ks = 0; ks < 2; ++ks) {
            const int g = ks * 4 + q;
            bf16x8 af[4], bfr[4];
            #pragma unroll
            for (int mi = 0; mi < 4; ++mi)
                af[mi] = *(const bf16x8*)&Asm[(wm + mi * 16 + l15) * 72 + g * 8];
            #pragma unroll
            for (int ni = 0; ni < 4; ++ni) {
                int n = wn + ni * 16 + l15;
                bfr[ni] = *(const bf16x8*)&Bsm[n * 64 + (g ^ (n & 7)) * 8];
            }
            #pragma unroll
            for (int mi = 0; mi < 4; ++mi)
                #pragma unroll
                for (int ni = 0; ni < 4; ++ni)
                    acc[mi][ni] = __builtin_amdgcn_mfma_f32_16x16x32_bf16(
                        af[mi], bfr[ni], acc[mi][ni], 0, 0, 0);
        }
        __syncthreads();
    }

    int growv[16];
    #pragma unroll
    for (int mi = 0; mi < 4; ++mi)
        #pragma unroll
        for (int r = 0; r < 4; ++r) {
            int rloc = wm + mi * 16 + q * 4 + r;
            growv[mi * 4 + r] = (rloc < m_valid) ? rl[rloc] : -1;
        }
    const int ncol0 = nt * 128 + wn;
    #pragma unroll
    for (int ni = 0; ni < 4; ++ni) {
        int col = ncol0 + ni * 16 + l15;
        float bv = bias[e * NDIM + col];
        #pragma unroll
        for (int mi = 0; mi < 4; ++mi)
            #pragma unroll
            for (int r = 0; r < 4; ++r) {
                int gr = growv[mi * 4 + r];
                if (gr >= 0) out[(size_t)gr * NDIM + col] = acc[mi][ni][r] + bv;
            }
    }
}

extern "C" void kernel_launch(void* const* d_in, const int* in_sizes, int n_in,
                              void* d_out, int out_size, void* d_ws, size_t ws_size,
                              hipStream_t stream) {
    const float* x      = (const float*)d_in[0];   // (16384, 512) f32
    const int*   groups = (const int*)d_in[1];     // (16384, 2) i32
    const float* W      = (const float*)d_in[2];   // (8, 512, 512) f32
    const float* b      = (const float*)d_in[3];   // (8, 512) f32
    float*       out    = (float*)d_out;           // (16384, 512) f32

    char* ws = (char*)d_ws;
    int*            counts  = (int*)ws;
    int*            ndesc   = (int*)(ws + WS_NDESC_OFF);
    int*            desc    = (int*)(ws + WS_DESC_OFF);
    int*            rowlist = (int*)(ws + WS_ROWLIST_OFF);
    unsigned short* Wtile   = (unsigned short*)(ws + WS_WT_OFF);
    unsigned short* xg      = (unsigned short*)(ws + WS_XG_OFF);

    zero_kernel<<<1, 64, 0, stream>>>(counts);
    prep_kernel<<<320, 256, 0, stream>>>(W, groups, counts, rowlist, Wtile);
    plan_kernel<<<1, 64, 0, stream>>>(counts, ndesc, desc);
    if (ws_size >= WS_NEED) {
        gather_kernel<<<MAX_DESC * 8, 256, 0, stream>>>(x, counts, rowlist,
                                                        ndesc, desc, xg);
        gemm_tiled<<<MAX_DESC * 4, 256, 0, stream>>>(xg, counts, rowlist,
                                                     Wtile, b, out, ndesc, desc);
    } else {
        gemm_fb<<<4096, 256, 0, stream>>>(x, counts, rowlist, Wtile, b, out);
    }
}

// Round 6
// 130.228 us; speedup vs baseline: 1.1000x; 1.0063x over previous
//
#include <hip/hip_runtime.h>
#include <hip/hip_bf16.h>

// SubnetGate = gathered grouped GEMM (B=16384, K=512, N=512, E=8, col 0).
// R6: same as R5 except gemm_tiled is double-buffered (A+B, 48KB LDS,
// 3 blocks/CU): per kt, fragments are ds_read first (vmcnt drain only hits
// loads issued one full iteration earlier), then async global_load_lds for
// kt+1 is issued, then 16 MFMAs run, then one barrier. Staging latency is
// overlapped with the MFMA block instead of serialized.
//
// ws layout:
//   [0,32)      int counts[8]
//   [64,68)     int ndesc
//   [128,1184)  int desc[264]            (e<<16 | mt), BM=64 tiles
//   [4096,528384)      int rowlist[8][16384]
//   [528384,4722688)   ushort Wtile[8][4 nt][8 kt][128n x 64k bf16, swizzled]
//   [4722688,22024192) ushort xg[264 d][8 kt][64m x 64k bf16, swizzled]

#define NROWS   16384
#define KDIM    512
#define NDIM    512
#define NEXP    8
#define TILE_ELEMS 8192                  // B tile: 128n x 64k shorts (16KB)
#define ATILE_ELEMS 4096                 // A tile: 64m x 64k shorts (8KB)
#define MAX_DESC 264
#define WS_NDESC_OFF   64
#define WS_DESC_OFF    128
#define WS_ROWLIST_OFF 4096
#define WS_WT_OFF      (4096 + NEXP * NROWS * 4)
#define WS_XG_OFF      (WS_WT_OFF + NEXP * KDIM * NDIM * 2)
#define WS_NEED        ((size_t)WS_XG_OFF + (size_t)MAX_DESC * 8 * ATILE_ELEMS * 2)

typedef __bf16        bf16x8 __attribute__((ext_vector_type(8)));
typedef float         f32x4  __attribute__((ext_vector_type(4)));
typedef unsigned int  u32x4  __attribute__((ext_vector_type(4)));

__device__ __forceinline__ unsigned int f2bf_u(float f) {
    unsigned int u = __builtin_bit_cast(unsigned int, f);
    return (u + 0x7FFFu + ((u >> 16) & 1u)) >> 16;   // RNE f32->bf16
}
__device__ __forceinline__ unsigned int pack2(float a, float b) {
    return f2bf_u(a) | (f2bf_u(b) << 16);
}
__device__ __forceinline__ u32x4 pack8(f32x4 a, f32x4 b) {
    u32x4 p;
    p.x = pack2(a.x, a.y); p.y = pack2(a.z, a.w);
    p.z = pack2(b.x, b.y); p.w = pack2(b.z, b.w);
    return p;
}
__device__ __forceinline__ void gl_lds16(const void* g, void* l) {
    __builtin_amdgcn_global_load_lds(
        (const __attribute__((address_space(1))) unsigned int*)g,
        (__attribute__((address_space(3))) unsigned int*)l, 16, 0, 0);
}

__global__ void zero_kernel(int* __restrict__ gcnt) {
    if (threadIdx.x < NEXP) gcnt[threadIdx.x] = 0;
}

// blocks [0,256): build one 16KB swizzled B-tile (e,nt,kt); granule (n,g) at
//   shorts n*64 + (g^(n&7))*8. [verified R3/R5]
// blocks [256,320): histogram+scatter rows into per-expert rowlists.
__global__ void prep_kernel(const float* __restrict__ W,
                            const int* __restrict__ groups,
                            int* __restrict__ gcnt,
                            int* __restrict__ rowlist,
                            unsigned short* __restrict__ Wtile) {
    __shared__ __align__(16) unsigned short tl[TILE_ELEMS];
    __shared__ int lcnt[NEXP];
    __shared__ int lbase[NEXP];
    const int bid = blockIdx.x;
    const int tid = threadIdx.x;

    if (bid < 256) {
        const int e  = bid >> 5;         // bid = e*32 + nt*8 + kt
        const int nt = (bid >> 3) & 3;
        const int kt = bid & 7;
        const float* Wb = W + (size_t)e * (KDIM * NDIM);
        #pragma unroll
        for (int i = 0; i < 4; ++i) {
            int f = i * 256 + tid;       // granule id 0..1023
            int n = f & 127;
            int g = f >> 7;
            int col = nt * 128 + n;
            unsigned int p[4];
            #pragma unroll
            for (int jj = 0; jj < 4; ++jj) {
                int k0 = kt * 64 + g * 8 + jj * 2;
                p[jj] = pack2(Wb[(size_t)k0 * NDIM + col],
                              Wb[(size_t)(k0 + 1) * NDIM + col]);
            }
            *(u32x4*)&tl[n * 64 + (g ^ (n & 7)) * 8] = *(const u32x4*)p;
        }
        __syncthreads();
        unsigned short* dst = Wtile + (size_t)bid * TILE_ELEMS;
        #pragma unroll
        for (int i = 0; i < 4; ++i) {
            int off = (i * 256 + tid) * 8;
            *(u32x4*)&dst[off] = *(const u32x4*)&tl[off];
        }
    } else {
        const int base = (bid - 256) * 256;
        if (tid < NEXP) lcnt[tid] = 0;
        __syncthreads();
        int r = base + tid;
        int e = groups[r * 2];           // group_col = 0
        int pos = atomicAdd(&lcnt[e], 1);
        __syncthreads();
        if (tid < NEXP) lbase[tid] = atomicAdd(&gcnt[tid], lcnt[tid]);
        __syncthreads();
        rowlist[e * NROWS + lbase[e] + pos] = r;
    }
}

// desc[d] = (e<<16 | mt) for BM=64 m-tiles; ndesc = total descs.
__global__ void plan_kernel(const int* __restrict__ counts,
                            int* __restrict__ ndesc,
                            int* __restrict__ desc) {
    if (threadIdx.x == 0) {
        int M = 0;
        for (int e = 0; e < NEXP; ++e) {
            int nmt = (counts[e] + 63) >> 6;
            for (int mt = 0; mt < nmt && M < MAX_DESC; ++mt)
                desc[M++] = (e << 16) | mt;
        }
        ndesc[0] = M;
    }
}

// Block (d,kt): gather 64 rows x 64 k of x, cast bf16, write one 8KB swizzled
// A-tile: granule (m,g) at shorts m*64 + (g^(m&7))*8. [verified R5]
__global__ __launch_bounds__(256, 4)
void gather_kernel(const float* __restrict__ x,
                   const int* __restrict__ counts,
                   const int* __restrict__ rowlist,
                   const int* __restrict__ ndesc,
                   const int* __restrict__ desc,
                   unsigned short* __restrict__ xg) {
    const int bid = blockIdx.x;
    const int d  = bid >> 3;
    const int kt = bid & 7;
    if (d >= ndesc[0]) return;
    const int de = desc[d];
    const int e  = de >> 16;
    const int mt = de & 0xffff;
    const int cnt = counts[e];
    int m_valid = cnt - mt * 64;
    if (m_valid > 64) m_valid = 64;
    const int* rl = rowlist + e * NROWS + mt * 64;

    const int t = threadIdx.x;
    const int m = t >> 2;
    const int c = t & 3;                 // quarter: floats [c*16, c*16+16)

    u32x4 lo = {0u,0u,0u,0u}, hi = {0u,0u,0u,0u};
    if (m < m_valid) {
        const float* s = x + (size_t)rl[m] * KDIM + kt * 64 + c * 16;
        f32x4 v0 = *(const f32x4*)(s);
        f32x4 v1 = *(const f32x4*)(s + 4);
        f32x4 v2 = *(const f32x4*)(s + 8);
        f32x4 v3 = *(const f32x4*)(s + 12);
        lo = pack8(v0, v1);              // granule g0 = 2c
        hi = pack8(v2, v3);              // granule g1 = 2c+1
    }
    const int p = m & 7;
    unsigned short* tile = xg + ((size_t)d * 8 + kt) * ATILE_ELEMS;
    int base = (m * 8 + ((2 * c) ^ (p & 6))) * 8;    // shorts
    if (p & 1) {
        *(u32x4*)&tile[base]     = hi;
        *(u32x4*)&tile[base + 8] = lo;
    } else {
        *(u32x4*)&tile[base]     = lo;
        *(u32x4*)&tile[base + 8] = hi;
    }
}

// m97-style GEMM, now double-buffered. Tile (d,nt) = 64 rows x 128 cols,
// K=512 in 8 steps. Per kt: ds_read fragments (drain hits loads from one
// iteration ago), issue async loads kt+1, MFMA x16, barrier.
__global__ __launch_bounds__(256, 3)
void gemm_tiled(const unsigned short* __restrict__ xg,
                const int* __restrict__ counts,
                const int* __restrict__ rowlist,
                const unsigned short* __restrict__ Wtile,
                const float* __restrict__ bias,
                float* __restrict__ out,
                const int* __restrict__ ndesc,
                const int* __restrict__ desc) {
    __shared__ __align__(16) unsigned short Asm[2][ATILE_ELEMS];   // 2 x 8KB
    __shared__ __align__(16) unsigned short Bsm[2][TILE_ELEMS];    // 2 x 16KB

    const int tid = threadIdx.x;
    const int w   = tid >> 6;
    const int ln  = tid & 63;
    const int q   = ln >> 4;
    const int l15 = ln & 15;
    const int wm  = (w >> 1) * 32;
    const int wn  = (w & 1) * 64;

    const int T = ndesc[0] * 4;
    for (int tix = blockIdx.x; tix < T; tix += gridDim.x) {
        const int d  = tix >> 2;
        const int nt = tix & 3;
        const int de = desc[d];
        const int e  = de >> 16;
        const int mt = de & 0xffff;
        const int cnt = counts[e];
        int m_valid = cnt - mt * 64;
        if (m_valid > 64) m_valid = 64;
        const int* rl = rowlist + e * NROWS + mt * 64;

        const unsigned short* atile = xg + (size_t)d * 8 * ATILE_ELEMS;
        const unsigned short* btile = Wtile + (size_t)(e * 32 + nt * 8) * TILE_ELEMS;

        f32x4 acc[2][4];
        #pragma unroll
        for (int mi = 0; mi < 2; ++mi)
            #pragma unroll
            for (int ni = 0; ni < 4; ++ni)
                acc[mi][ni] = (f32x4){0.f, 0.f, 0.f, 0.f};

        // ---- preload kt=0 into buffer 0
        #pragma unroll
        for (int i = 0; i < 2; ++i) {
            int off = (i * 256 + tid) * 8;
            gl_lds16(atile + off, &Asm[0][off]);
        }
        #pragma unroll
        for (int i = 0; i < 4; ++i) {
            int off = (i * 256 + tid) * 8;
            gl_lds16(btile + off, &Bsm[0][off]);
        }
        __syncthreads();                 // drains vmcnt -> buf0 ready

        #pragma unroll 1
        for (int kt = 0; kt < 8; ++kt) {
            const int cur = kt & 1;
            // ---- ds_read ALL fragments for kt (prev prefetch long landed)
            bf16x8 af[2][2], bfr[2][4];
            #pragma unroll
            for (int ks = 0; ks < 2; ++ks) {
                const int g = ks * 4 + q;
                #pragma unroll
                for (int mi = 0; mi < 2; ++mi) {
                    int r = wm + mi * 16 + l15;
                    af[ks][mi] = *(const bf16x8*)&Asm[cur][(r * 8 + (g ^ (r & 7))) * 8];
                }
                #pragma unroll
                for (int ni = 0; ni < 4; ++ni) {
                    int n = wn + ni * 16 + l15;
                    bfr[ks][ni] = *(const bf16x8*)&Bsm[cur][n * 64 + (g ^ (n & 7)) * 8];
                }
            }
            __builtin_amdgcn_sched_barrier(0);   // keep ds_reads above prefetch
            // ---- issue async stage of kt+1 into the other buffer
            if (kt < 7) {
                const unsigned short* an = atile + (kt + 1) * ATILE_ELEMS;
                const unsigned short* bn = btile + (kt + 1) * TILE_ELEMS;
                #pragma unroll
                for (int i = 0; i < 2; ++i) {
                    int off = (i * 256 + tid) * 8;
                    gl_lds16(an + off, &Asm[cur ^ 1][off]);
                }
                #pragma unroll
                for (int i = 0; i < 4; ++i) {
                    int off = (i * 256 + tid) * 8;
                    gl_lds16(bn + off, &Bsm[cur ^ 1][off]);
                }
            }
            // ---- compute kt (prefetch in flight underneath)
            #pragma unroll
            for (int ks = 0; ks < 2; ++ks)
                #pragma unroll
                for (int mi = 0; mi < 2; ++mi)
                    #pragma unroll
                    for (int ni = 0; ni < 4; ++ni)
                        acc[mi][ni] = __builtin_amdgcn_mfma_f32_16x16x32_bf16(
                            af[ks][mi], bfr[ks][ni], acc[mi][ni], 0, 0, 0);
            __syncthreads();             // drains prefetch; guards buffer reuse
        }

        // epilogue: +bias, masked scatter (C/D: col=l15, row=q*4+r)
        int growv[8];
        #pragma unroll
        for (int mi = 0; mi < 2; ++mi)
            #pragma unroll
            for (int r = 0; r < 4; ++r) {
                int rloc = wm + mi * 16 + q * 4 + r;
                growv[mi * 4 + r] = (rloc < m_valid) ? rl[rloc] : -1;
            }
        const int ncol0 = nt * 128 + wn;
        #pragma unroll
        for (int ni = 0; ni < 4; ++ni) {
            int col = ncol0 + ni * 16 + l15;
            float bv = bias[e * NDIM + col];
            #pragma unroll
            for (int mi = 0; mi < 2; ++mi)
                #pragma unroll
                for (int r = 0; r < 4; ++r) {
                    int gr = growv[mi * 4 + r];
                    if (gr >= 0) out[(size_t)gr * NDIM + col] = acc[mi][ni][r] + bv;
                }
        }
    }
}

// Fallback (ws too small for xg): R3-verified gemm. BM=BN=128, in-kernel
// A gather+pack, B via global_load_lds from Wtile.
__global__ __launch_bounds__(256, 2)
void gemm_fb(const float* __restrict__ x,
             const int* __restrict__ counts,
             const int* __restrict__ rowlist,
             const unsigned short* __restrict__ Wtile,
             const float* __restrict__ bias,
             float* __restrict__ out) {
    __shared__ __align__(16) unsigned short Asm[128 * 72];
    __shared__ __align__(16) unsigned short Bsm[TILE_ELEMS];

    const int bid = blockIdx.x;
    const int e   = bid >> 9;
    const int mt  = (bid >> 2) & 127;
    const int nt  = bid & 3;
    const int cnt = counts[e];
    const int rb  = mt * 128;
    if (rb >= cnt) return;
    int m_valid = cnt - rb;
    if (m_valid > 128) m_valid = 128;
    const int* rl = rowlist + e * NROWS + rb;

    const int tid = threadIdx.x;
    const int w   = tid >> 6;
    const int ln  = tid & 63;
    const int q   = ln >> 4;
    const int l15 = ln & 15;
    const int wm  = (w >> 1) * 64;
    const int wn  = (w & 1) * 64;

    const float* srcp[4];
    int lm[4], lg[4];
    #pragma unroll
    for (int i = 0; i < 4; ++i) {
        int f = i * 256 + tid;
        lm[i] = f >> 3;
        lg[i] = f & 7;
        srcp[i] = (lm[i] < m_valid) ? (x + (size_t)rl[lm[i]] * KDIM + lg[i] * 8)
                                    : nullptr;
    }
    const unsigned short* wt = Wtile + (size_t)(e * 32 + nt * 8) * TILE_ELEMS;

    f32x4 acc[4][4];
    #pragma unroll
    for (int mi = 0; mi < 4; ++mi)
        #pragma unroll
        for (int ni = 0; ni < 4; ++ni)
            acc[mi][ni] = (f32x4){0.f, 0.f, 0.f, 0.f};

    for (int kt = 0; kt < 8; ++kt) {
        const unsigned short* wsrc = wt + (size_t)kt * TILE_ELEMS;
        #pragma unroll
        for (int i = 0; i < 4; ++i) {
            int off = (i * 256 + tid) * 8;
            gl_lds16(wsrc + off, &Bsm[off]);
        }
        #pragma unroll
        for (int i = 0; i < 4; ++i) {
            u32x4 p = {0u, 0u, 0u, 0u};
            if (srcp[i]) {
                const float* s = srcp[i] + kt * 64;
                p = pack8(*(const f32x4*)s, *(const f32x4*)(s + 4));
            }
            *(u32x4*)&Asm[lm[i] * 72 + lg[i] * 8] = p;
        }
        __syncthreads();
        #pragma unroll
        for (int ks = 0; ks < 2; ++ks) {
            const int g = ks * 4 + q;
            bf16x8 af[4], bfr[4];
            #pragma unroll
            for (int mi = 0; mi < 4; ++mi)
                af[mi] = *(const bf16x8*)&Asm[(wm + mi * 16 + l15) * 72 + g * 8];
            #pragma unroll
            for (int ni = 0; ni < 4; ++ni) {
                int n = wn + ni * 16 + l15;
                bfr[ni] = *(const bf16x8*)&Bsm[n * 64 + (g ^ (n & 7)) * 8];
            }
            #pragma unroll
            for (int mi = 0; mi < 4; ++mi)
                #pragma unroll
                for (int ni = 0; ni < 4; ++ni)
                    acc[mi][ni] = __builtin_amdgcn_mfma_f32_16x16x32_bf16(
                        af[mi], bfr[ni], acc[mi][ni], 0, 0, 0);
        }
        __syncthreads();
    }

    int growv[16];
    #pragma unroll
    for (int mi = 0; mi < 4; ++mi)
        #pragma unroll
        for (int r = 0; r < 4; ++r) {
            int rloc = wm + mi * 16 + q * 4 + r;
            growv[mi * 4 + r] = (rloc < m_valid) ? rl[rloc] : -1;
        }
    const int ncol0 = nt * 128 + wn;
    #pragma unroll
    for (int ni = 0; ni < 4; ++ni) {
        int col = ncol0 + ni * 16 + l15;
        float bv = bias[e * NDIM + col];
        #pragma unroll
        for (int mi = 0; mi < 4; ++mi)
            #pragma unroll
            for (int r = 0; r < 4; ++r) {
                int gr = growv[mi * 4 + r];
                if (gr >= 0) out[(size_t)gr * NDIM + col] = acc[mi][ni][r] + bv;
            }
    }
}

extern "C" void kernel_launch(void* const* d_in, const int* in_sizes, int n_in,
                              void* d_out, int out_size, void* d_ws, size_t ws_size,
                              hipStream_t stream) {
    const float* x      = (const float*)d_in[0];   // (16384, 512) f32
    const int*   groups = (const int*)d_in[1];     // (16384, 2) i32
    const float* W      = (const float*)d_in[2];   // (8, 512, 512) f32
    const float* b      = (const float*)d_in[3];   // (8, 512) f32
    float*       out    = (float*)d_out;           // (16384, 512) f32

    char* ws = (char*)d_ws;
    int*            counts  = (int*)ws;
    int*            ndesc   = (int*)(ws + WS_NDESC_OFF);
    int*            desc    = (int*)(ws + WS_DESC_OFF);
    int*            rowlist = (int*)(ws + WS_ROWLIST_OFF);
    unsigned short* Wtile   = (unsigned short*)(ws + WS_WT_OFF);
    unsigned short* xg      = (unsigned short*)(ws + WS_XG_OFF);

    zero_kernel<<<1, 64, 0, stream>>>(counts);
    prep_kernel<<<320, 256, 0, stream>>>(W, groups, counts, rowlist, Wtile);
    plan_kernel<<<1, 64, 0, stream>>>(counts, ndesc, desc);
    if (ws_size >= WS_NEED) {
        gather_kernel<<<MAX_DESC * 8, 256, 0, stream>>>(x, counts, rowlist,
                                                        ndesc, desc, xg);
        gemm_tiled<<<MAX_DESC * 4, 256, 0, stream>>>(xg, counts, rowlist,
                                                     Wtile, b, out, ndesc, desc);
    } else {
        gemm_fb<<<4096, 256, 0, stream>>>(x, counts, rowlist, Wtile, b, out);
    }
}